// Round 1
// 196.649 us; speedup vs baseline: 1.0705x; 1.0705x over previous
//
#include <hip/hip_runtime.h>

#define FIN 100
#define FHID 100
#define FEMB 64
#define NCLS 40
#define H1STR 112             // padded row stride for h1/a1r: 14 x ushort8, 224B rows (16B aligned)

#define SBSH 8                // 256 nodes per super-bucket
#define CAPB 24               // LDS bin capacity per block
#define SBCAP 4608            // per-super-bucket arena cap
#define CSTR 16               // cursor stride in ints
#define EPB 2048              // edges per scatter block

typedef __attribute__((ext_vector_type(8))) short short8;          // MFMA A/B frag
typedef __attribute__((ext_vector_type(8))) unsigned short u16x8;  // 16B bf16 gather
typedef __attribute__((ext_vector_type(4))) float f32x4;           // MFMA C/D frag

// ---------- bf16 helpers (RNE) ----------
__device__ inline unsigned short f2bf(float f) {
    unsigned u = __float_as_uint(f);
    u += 0x7FFFu + ((u >> 16) & 1u);
    return (unsigned short)(u >> 16);
}
__device__ inline float bf2f(unsigned short s) {
    return __uint_as_float((unsigned)s << 16);
}

// ====== MFMA compute + epilogue on staged LDS tiles (16x16x32 bf16, layouts per learn_hip m89/m91) ======
template <int KP, int KOUT, int NTY, bool BIAS, bool OUT_BF16, int OSTR>
__device__ __forceinline__ void mfma_tiles(const unsigned short* Abf, const unsigned short* Wt,
                                           const float* __restrict__ bias, void* __restrict__ C,
                                           int n, int row0, int tb) {
    constexpr int APAD  = KP + 8;
    constexpr int NKC   = KP / 32;
    constexpr int TQ    = (NTY + 1) / 2;
    constexpr int NTALL = (KOUT + 15) / 16;

    const int tid  = threadIdx.x;
    const int lane = tid & 63;
    const int w    = tid >> 6;
    const int m0   = (w >> 1) * 64;
    const int t0   = (w & 1) * TQ;
    const int lm   = lane & 15;
    const int quad = lane >> 4;

    const int ntloc = (NTALL - tb < NTY) ? (NTALL - tb) : NTY;
    const int tcnt  = (ntloc - t0 < TQ) ? (ntloc - t0) : TQ;

    f32x4 acc[4][TQ];
    #pragma unroll
    for (int i = 0; i < 4; ++i)
        #pragma unroll
        for (int t = 0; t < TQ; ++t)
            acc[i][t] = (f32x4)(0.f);

    for (int kt = 0; kt < NKC; ++kt) {
        short8 a[4], b[TQ];
        #pragma unroll
        for (int i = 0; i < 4; ++i)
            a[i] = *(const short8*)&Abf[(m0 + i * 16 + lm) * APAD + kt * 32 + quad * 8];
        #pragma unroll
        for (int t = 0; t < TQ; ++t)
            if (t < tcnt)
                b[t] = *(const short8*)&Wt[((t0 + t) * 16 + lm) * APAD + kt * 32 + quad * 8];
        #pragma unroll
        for (int i = 0; i < 4; ++i)
            #pragma unroll
            for (int t = 0; t < TQ; ++t)
                if (t < tcnt)
                    acc[i][t] = __builtin_amdgcn_mfma_f32_16x16x32_bf16(a[i], b[t], acc[i][t], 0, 0, 0);
    }

    #pragma unroll
    for (int t = 0; t < TQ; ++t) {
        if (t >= tcnt) continue;
        int col = (tb + t0 + t) * 16 + lm;
        if (col >= KOUT) continue;
        float bv = 0.f;
        if constexpr (BIAS) bv = bias[col];
        #pragma unroll
        for (int i = 0; i < 4; ++i) {
            #pragma unroll
            for (int rg = 0; rg < 4; ++rg) {
                int row = row0 + m0 + i * 16 + quad * 4 + rg;
                if (row < n) {
                    float v = acc[i][t][rg] + bv;
                    if constexpr (OUT_BF16)
                        ((unsigned short*)C)[(size_t)row * OSTR + col] = f2bf(v);
                    else
                        ((float*)C)[(size_t)row * OSTR + col] = v;
                }
            }
        }
    }
}

// ====== full GEMM body: stage A(+pads) once, per-pass stage Wt, compute ======
template <int KIN, int KOUT, int NTY, bool A_BF16, bool BIAS, bool OUT_BF16, int ASTR, int OSTR>
__device__ __forceinline__ void gemm_body(const void* __restrict__ A, const float* __restrict__ W,
                                          const float* __restrict__ bias, void* __restrict__ C,
                                          int n, int bid, char* smem) {
    constexpr int KP    = ((KIN + 31) / 32) * 32;
    constexpr int NTALL = (KOUT + 15) / 16;
    constexpr int NTC   = NTY * 16;
    constexpr int APAD  = KP + 8;
    constexpr int KQ4   = KIN / 4;
    static_assert(KIN % 4 == 0 && ASTR % 4 == 0, "quad staging");

    unsigned short* Abf = (unsigned short*)smem;               // 128 * APAD
    unsigned short* Wt  = Abf + 128 * APAD;                    // NTC * APAD

    const int row0 = bid * 128;
    const int tid  = threadIdx.x;

    // ---- stage A tile as bf16 (once) ----
    if constexpr (A_BF16) {
        const ushort4* A4 = (const ushort4*)A;
        constexpr int AQ = ASTR / 4;
        for (int idx = tid; idx < 128 * KQ4; idx += 256) {
            int r = idx / KQ4;
            int kq = idx - r * KQ4;
            ushort4 v = make_ushort4(0, 0, 0, 0);
            if (row0 + r < n) v = A4[(size_t)(row0 + r) * AQ + kq];
            *(ushort4*)&Abf[r * APAD + kq * 4] = v;
        }
    } else {
        const float* Af = (const float*)A;
        for (int idx = tid; idx < 128 * KQ4; idx += 256) {
            int r = idx / KQ4;
            int kq = idx - r * KQ4;
            float4 v = make_float4(0.f, 0.f, 0.f, 0.f);
            if (row0 + r < n) v = ((const float4*)(Af + (size_t)(row0 + r) * ASTR))[kq];
            ushort4 o;
            o.x = f2bf(v.x); o.y = f2bf(v.y); o.z = f2bf(v.z); o.w = f2bf(v.w);
            *(ushort4*)&Abf[r * APAD + kq * 4] = o;
        }
    }
    if constexpr (KP > KIN) {
        constexpr int PADW = KP - KIN;
        for (int idx = tid; idx < 128 * PADW; idx += 256) {
            int r = idx / PADW;
            Abf[r * APAD + KIN + (idx - r * PADW)] = 0;
        }
    }
    // ---- zero output pad columns (so downstream ushort8 aggregation reads exact zeros) ----
    if constexpr (OUT_BF16 && (OSTR > KOUT)) {
        constexpr int PW = OSTR - KOUT;
        for (int idx = tid; idx < 128 * PW; idx += 256) {
            int r = idx / PW;
            int c = idx - r * PW;
            if (row0 + r < n)
                ((unsigned short*)C)[(size_t)(row0 + r) * OSTR + KOUT + c] = 0;
        }
    }

    // ---- pass loop over column-tile groups ----
    for (int tb = 0; tb < NTALL; tb += NTY) {
        for (int idx = tid; idx < KIN * NTC; idx += 256) {
            int k = idx / NTC;
            int c = idx - k * NTC;
            int gc = (tb + 0) * 16 + c;
            float v = (gc < KOUT) ? W[(size_t)k * KOUT + gc] : 0.f;
            Wt[c * APAD + k] = f2bf(v);
        }
        if constexpr (KP > KIN) {
            constexpr int PADW = KP - KIN;
            for (int idx = tid; idx < NTC * PADW; idx += 256) {
                int c = idx / PADW;
                Wt[c * APAD + KIN + (idx - c * PADW)] = 0;
            }
        }
        __syncthreads();
        mfma_tiles<KP, KOUT, NTY, BIAS, OUT_BF16, OSTR>(Abf, Wt, bias, C, n, row0, tb);
        __syncthreads();   // protect Wt before next pass restage
    }
}

// ====== standalone GEMM wrapper ======
template <int KIN, int KOUT, int NTY, bool A_BF16, bool BIAS, bool OUT_BF16, int ASTR, int OSTR>
__global__ __launch_bounds__(256) void k_gemm_mfma(const void* __restrict__ A,
                                                   const float* __restrict__ W,
                                                   const float* __restrict__ bias,
                                                   void* __restrict__ C, int n) {
    constexpr int KP   = ((KIN + 31) / 32) * 32;
    constexpr int APAD = KP + 8;
    constexpr int NTC  = NTY * 16;
    __shared__ __attribute__((aligned(16))) char smem[(128 + NTC) * APAD * 2];
    gemm_body<KIN, KOUT, NTY, A_BF16, BIAS, OUT_BF16, ASTR, OSTR>(A, W, bias, C, n, blockIdx.x, smem);
}

// ====== merged front: edge scatter-binning (blocks [0,scb)) || GEMM1 (blocks [scb, scb+nmb)) ======
// The two are independent; merging overlaps gemm1's ~10us under the scatter instead of serializing.
#define SMEM_FRONT ((128 + 64) * (128 + 8) * 2)   // = 52224B, gemm1 is the larger user
__global__ __launch_bounds__(256) void k_front(const int* __restrict__ src,
                                               const int* __restrict__ dst,
                                               int* __restrict__ gcur,
                                               int* __restrict__ arena,
                                               int E, int nsb, int scb,
                                               const float* __restrict__ x,
                                               const float* __restrict__ W1,
                                               unsigned short* __restrict__ h1, int n) {
    __shared__ __attribute__((aligned(16))) char smem[SMEM_FRONT];
    static_assert(SMEM_FRONT >= (int)(256 * CAPB * 4 + 2 * 256 * 4), "scatter fits");
    if ((int)blockIdx.x < scb) {
        // ---- scatter path: LDS-binned coalesced burst appends to per-super-bucket arenas ----
        int* bins  = (int*)smem;            // 256*CAPB
        int* bcnt  = bins + 256 * CAPB;     // 256
        int* pbase = bcnt + 256;            // 256
        const int tid = threadIdx.x;
        bcnt[tid] = 0;
        __syncthreads();

        const int e0 = blockIdx.x * EPB;
        #pragma unroll
        for (int k = 0; k < EPB / 256; ++k) {
            int e = e0 + k * 256 + tid;
            if (e < E) {
                int d = dst[e];
                int sb = d >> SBSH;
                int rec = (src[e] << SBSH) | (d & 255);
                int c = atomicAdd(&bcnt[sb], 1);
                if (c < CAPB) {
                    bins[sb * CAPB + c] = rec;
                } else {  // rare overflow: direct global append
                    int p = atomicAdd(&gcur[sb * CSTR], 1);
                    if (p < SBCAP) arena[(size_t)sb * SBCAP + p] = rec;
                }
            }
        }
        __syncthreads();

        if (tid < nsb) {
            int c = bcnt[tid];
            if (c > CAPB) c = CAPB;
            pbase[tid] = (c > 0) ? atomicAdd(&gcur[tid * CSTR], c) : 0;
        }
        __syncthreads();

        const int wv = tid >> 6, lane = tid & 63;
        for (int sb = wv; sb < nsb; sb += 4) {
            int c = bcnt[sb];
            if (c > CAPB) c = CAPB;
            int p = pbase[sb];
            if (lane < c && p + lane < SBCAP)
                arena[(size_t)sb * SBCAP + p + lane] = bins[sb * CAPB + lane];
        }
    } else {
        // ---- GEMM1 path: h1(bf16, stride H1STR, pad cols zeroed) = x @ W1 ----
        gemm_body<FIN, FHID, 4, false, false, true, FIN, H1STR>(
            x, W1, nullptr, h1, n, (int)blockIdx.x - scb, smem);
    }
}

// ====== per-super-bucket sort: 1024 threads (4x the old intra-block parallelism) ======
__global__ __launch_bounds__(1024) void k_bucket_sort(const int* __restrict__ arena,
                                                      const int* __restrict__ gcur,
                                                      int* __restrict__ gcounter,
                                                      int* __restrict__ rowptr,
                                                      int* __restrict__ rowend,
                                                      float* __restrict__ dinv,
                                                      int* __restrict__ src_sorted, int n) {
    const int sb = blockIdx.x;
    const int tid = threadIdx.x;
    __shared__ int cnt[256], off[256], tmp[256];
    __shared__ int base_sh;
    if (tid < 256) cnt[tid] = 0;
    __syncthreads();

    int len = gcur[sb * CSTR];
    if (len > SBCAP) len = SBCAP;
    const int* seg = arena + (size_t)sb * SBCAP;
    for (int i = tid; i < len; i += 1024)
        atomicAdd(&cnt[seg[i] & 255], 1);
    __syncthreads();

    // exclusive scan of cnt (Hillis-Steele over 256 counters; extra threads idle at barriers)
    int v = 0;
    if (tid < 256) { v = cnt[tid]; tmp[tid] = v; }
    __syncthreads();
    for (int o = 1; o < 256; o <<= 1) {
        int t = (tid >= o && tid < 256) ? tmp[tid - o] : 0;
        __syncthreads();
        if (tid < 256) tmp[tid] += t;
        __syncthreads();
    }
    if (tid < 256) off[tid] = tmp[tid] - v;  // exclusive
    if (tid == 255) base_sh = atomicAdd(gcounter, tmp[255]);
    __syncthreads();

    const int base = base_sh;
    if (tid < 256) {
        int node = (sb << SBSH) + tid;
        if (node < n) {
            int r0 = base + off[tid];
            rowptr[node] = r0;
            rowend[node] = r0 + v;
            dinv[node] = rsqrtf((float)v + 1.0f);  // +1 self-loop
        }
    }
    __syncthreads();

    // place (off doubles as cursor)
    for (int i = tid; i < len; i += 1024) {
        int rec = seg[i];
        int lpos = atomicAdd(&off[rec & 255], 1);
        src_sorted[base + lpos] = rec >> SBSH;
    }
}

// ====== CSR aggregation, 16B (ushort8) gathers: half the load-issue count, 2x in-flight bytes ======
// F = real feature count, NG = ushort8 groups per row, HSTR = row stride (ushorts) for in AND out.
template <int F, int NG, int HSTR>
__global__ __launch_bounds__(256) void k_agg8(const unsigned short* __restrict__ h,
                                              const int* __restrict__ rowptr,
                                              const int* __restrict__ rowend,
                                              const int* __restrict__ src_sorted,
                                              const float* __restrict__ dinv,
                                              const float* __restrict__ ab,
                                              unsigned short* __restrict__ out, int n) {
    int gid = blockIdx.x * 256 + threadIdx.x;
    if (gid >= n * NG) return;
    int i  = gid / NG;
    int c8 = gid - i * NG;
    const int co = c8 * 8;

    float a[8];
    #pragma unroll
    for (int j = 0; j < 8; ++j) a[j] = 0.f;

    int e = rowptr[i];
    const int end = rowend[i];
    for (; e + 3 < end; e += 4) {
        int s0 = src_sorted[e];
        int s1 = src_sorted[e + 1];
        int s2 = src_sorted[e + 2];
        int s3 = src_sorted[e + 3];
        u16x8 u0 = *(const u16x8*)&h[(size_t)s0 * HSTR + co];
        u16x8 u1 = *(const u16x8*)&h[(size_t)s1 * HSTR + co];
        u16x8 u2 = *(const u16x8*)&h[(size_t)s2 * HSTR + co];
        u16x8 u3 = *(const u16x8*)&h[(size_t)s3 * HSTR + co];
        float n0 = dinv[s0], n1 = dinv[s1], n2 = dinv[s2], n3 = dinv[s3];
        #pragma unroll
        for (int j = 0; j < 8; ++j) {
            a[j] = fmaf(bf2f(u0[j]), n0, a[j]);
            a[j] = fmaf(bf2f(u1[j]), n1, a[j]);
            a[j] = fmaf(bf2f(u2[j]), n2, a[j]);
            a[j] = fmaf(bf2f(u3[j]), n3, a[j]);
        }
    }
    for (; e < end; ++e) {
        int s = src_sorted[e];
        u16x8 u = *(const u16x8*)&h[(size_t)s * HSTR + co];
        float nn = dinv[s];
        #pragma unroll
        for (int j = 0; j < 8; ++j) a[j] = fmaf(bf2f(u[j]), nn, a[j]);
    }

    float d = dinv[i];
    u16x8 hv = *(const u16x8*)&h[(size_t)i * HSTR + co];
    u16x8 st;
    #pragma unroll
    for (int j = 0; j < 8; ++j) {
        int col = co + j;
        float bj = (col < F) ? ab[col] : 0.f;   // predicated: no OOB fault on pad group
        float r = fmaf(d, fmaf(d, bf2f(hv[j]), a[j]), bj);
        st[j] = f2bf(fmaxf(r, 0.f));
    }
    *(u16x8*)&out[(size_t)i * HSTR + co] = st;
}

extern "C" void kernel_launch(void* const* d_in, const int* in_sizes, int n_in,
                              void* d_out, int out_size, void* d_ws, size_t ws_size,
                              hipStream_t stream) {
    const float* x  = (const float*)d_in[0];
    const int*   ei = (const int*)d_in[1];
    const float* W1 = (const float*)d_in[2];
    const float* b1 = (const float*)d_in[3];
    const float* W2 = (const float*)d_in[4];
    const float* b2 = (const float*)d_in[5];
    const float* Wc = (const float*)d_in[6];
    const float* bc = (const float*)d_in[7];
    float* out = (float*)d_out;

    const int N = in_sizes[0] / FIN;
    const int E = in_sizes[1] / 2;
    const int* src = ei;
    const int* dst = ei + E;
    const int NSB = (N + 255) >> SBSH;
    const int SCB = (E + EPB - 1) / EPB;

    auto align = [](size_t v) { return (v + 255) & ~(size_t)255; };
    char* ws = (char*)d_ws;
    const size_t cur_bytes = align((size_t)256 * CSTR * 4 + 256);
    int*   gcur       = (int*)ws;   ws += cur_bytes;
    int*   gcounter   = gcur + 256 * CSTR;   // inside the memset region
    int*   arena      = (int*)ws;   ws += align((size_t)NSB * SBCAP * 4);
    int*   rowptr     = (int*)ws;   ws += align((size_t)N * 4);
    int*   rowend     = (int*)ws;   ws += align((size_t)N * 4);
    int*   src_sorted = (int*)ws;   ws += align((size_t)E * 4);
    float* dinv       = (float*)ws; ws += align((size_t)N * 4);
    unsigned short* h1  = (unsigned short*)ws; ws += align((size_t)N * H1STR * 2);
    unsigned short* a1r = (unsigned short*)ws; ws += align((size_t)N * H1STR * 2);
    unsigned short* h2  = (unsigned short*)ws; ws += align((size_t)N * FEMB * 2);
    unsigned short* a2r = (unsigned short*)ws; ws += align((size_t)N * FEMB * 2);

    const int B = 256;
    const int nmb = (N + 127) / 128;   // 391 MFMA row-tiles

    // 1) zero cursors + gcounter
    hipMemsetAsync(gcur, 0, cur_bytes, stream);

    // 2) merged: edge scatter (blocks [0,SCB)) || GEMM1 h1 = x@W1 (blocks [SCB,SCB+nmb))
    k_front<<<SCB + nmb, B, 0, stream>>>(src, dst, gcur, arena, E, NSB, SCB, x, W1, h1, N);

    // 3) per-super-bucket sort -> rowptr/rowend/dinv/src_sorted (1024 threads)
    k_bucket_sort<<<NSB, 1024, 0, stream>>>(arena, gcur, gcounter, rowptr, rowend, dinv, src_sorted, N);

    // 4) a1r = relu(agg(h1) + b1)   [13 ushort8 groups over 112-stride rows]
    k_agg8<FHID, 13, H1STR><<<((size_t)N * 13 + B - 1) / B, B, 0, stream>>>(
        h1, rowptr, rowend, src_sorted, dinv, b1, a1r, N);

    // 5) h2 = a1r @ W2
    k_gemm_mfma<FHID, FEMB, 4, true, false, true, H1STR, FEMB><<<nmb, B, 0, stream>>>(
        a1r, W2, nullptr, h2, N);

    // 6) a2r = relu(agg(h2) + b2)   [8 ushort8 groups, exact]
    k_agg8<FEMB, 8, FEMB><<<((size_t)N * 8 + B - 1) / B, B, 0, stream>>>(
        h2, rowptr, rowend, src_sorted, dinv, b2, a2r, N);

    // 7) out(fp32) = a2r @ Wc + bc
    k_gemm_mfma<FEMB, NCLS, 3, true, true, false, FEMB, NCLS><<<nmb, B, 0, stream>>>(
        a2r, Wc, bc, out, N);
}